// Round 1
// baseline (194.164 us; speedup 1.0000x reference)
//
#include <hip/hip_runtime.h>
#include <math.h>

// CTC batch cost (Keras ctc_batch_cost), gfx950. B=256,T=512,V=256,L=64,S=129.
//
// One wave = one batch element (256 blocks x 64 lanes). Lane L owns extended
// states 2L (blank) and 2L+1 (label L); lane 63 also owns s=128 privately.
//
// DP runs in LINEAR probability space (scaled forward algorithm):
//   na0   = (a0 + pa1) * pb
//   na1   = (a1 + a0 + skip*pa1) * pl
//   na128 = (a128 + a1) * pb          (lane 63 only meaningful)
// with pa1 = alpha[2L-1] fetched from the previous lane via DPP wave_shr:1
// (VALU, no LDS). Every 8 steps a wave-uniform max-rescale (DPP reduce +
// readlane + v_rcp) renormalizes and accumulates log2(norm) into logC.
// No transcendentals on the per-step critical path.
//
// y_pred streams via global_load_lds (16B/lane), QUAD-buffered 16-step
// tiles, issued THREE tiles ahead (48 KB in flight per CU ~ 12 MB chip-wide,
// above the loaded HBM BW-latency product), s_waitcnt vmcnt(32) in steady
// state; per tile only the blank column and each lane's label column are
// pulled from LDS into registers one tile ahead of use.

#define BB   256
#define TI   512
#define VV   256
#define LL   64
#define TT   16
#define NT   (TI / TT)          // 32 tiles
#define NBUF 4                  // quad buffer, 64 KB LDS
#define EPSF 1e-7f
#define LN2F 0.6931471805599453f

#if __has_builtin(__builtin_amdgcn_logf)
__device__ __forceinline__ float flog2(float x) { return __builtin_amdgcn_logf(x); }
#else
__device__ __forceinline__ float flog2(float x) { return __log2f(x); }
#endif

template <int CTRL>
__device__ __forceinline__ float dppf(float oldv, float v) {
    return __int_as_float(__builtin_amdgcn_update_dpp(
        __float_as_int(oldv), __float_as_int(v), CTRL, 0xF, 0xF, false));
}

// lane i <- lane i-1; lane 0 <- 0.0f  (v_mov_b32_dpp wave_shr:1)
__device__ __forceinline__ float shup0(float x) { return dppf<0x138>(0.0f, x); }

// wave-wide max, result broadcast via readlane(63). All inputs >= 0.
__device__ __forceinline__ float wave_max_bcast(float v) {
    v = fmaxf(v, dppf<0x111>(v, v));   // row_shr:1
    v = fmaxf(v, dppf<0x112>(v, v));   // row_shr:2
    v = fmaxf(v, dppf<0x114>(v, v));   // row_shr:4
    v = fmaxf(v, dppf<0x118>(v, v));   // row_shr:8
    v = fmaxf(v, dppf<0x142>(v, v));   // row_bcast:15
    v = fmaxf(v, dppf<0x143>(v, v));   // row_bcast:31  -> lane 63 has max
    return __int_as_float(__builtin_amdgcn_readlane(__float_as_int(v), 63));
}

__device__ __forceinline__ void rescale(float& a0, float& a1, float& a128,
                                        float& logC) {
    float m = wave_max_bcast(fmaxf(fmaxf(a0, a1), a128));
    m = fmaxf(m, 1e-37f);                       // paranoia: avoid 1/0
    float s = __builtin_amdgcn_rcpf(m);
    a0 *= s; a1 *= s; a128 *= s;
    logC += flog2(m);
}

__device__ __forceinline__ void dp_step(float& a0, float& a1, float& a128,
                                        float pb, float pl, float skipf) {
    float pa1 = shup0(a1);                      // alpha[2L-1]
    float s01 = a0 + a1;
    float t0  = a0 + pa1;
    float na1   = fmaf(pa1, skipf, s01) * pl;   // (a1+a0+skip*pa1)*pl
    float na0   = t0 * pb;                      // (a0+pa1)*pb
    float na128 = (a128 + a1) * pb;             // lane 63
    a0 = na0; a1 = na1; a128 = na128;
}

// stage one 16-timestep tile (16 KB) global -> LDS
__device__ __forceinline__ void stage_tile(const float* gsrc, float* lbase, int lane) {
    #pragma unroll
    for (int i = 0; i < TT; ++i) {
        __builtin_amdgcn_global_load_lds(
            (const __attribute__((address_space(1))) void*)(gsrc + i * VV + lane * 4),
            (__attribute__((address_space(3))) void*)(lbase + i * VV),
            16, 0, 0);
    }
}

// pull blank + own-label probabilities (with +eps folded in) into registers
__device__ __forceinline__ void prep_p(const float* sb, int myLab,
                                       float (&pb)[TT], float (&pl)[TT]) {
    #pragma unroll
    for (int tt = 0; tt < TT; ++tt) {
        pb[tt] = sb[tt * VV + (VV - 1)] + EPSF;
        pl[tt] = sb[tt * VV + myLab]    + EPSF;
    }
}

__global__ __launch_bounds__(64) void ctc_kernel(
        const int* __restrict__ y_true,
        const float* __restrict__ y_pred,
        float* __restrict__ out) {
    __shared__ float sbuf[NBUF * TT * VV];     // 64 KB quad buffer

    const int b    = blockIdx.x;
    const int lane = threadIdx.x;
    const float* src = y_pred + (size_t)b * TI * VV;

    const int myLab   = y_true[b * LL + lane];
    const int prevLab = __shfl_up(myLab, 1);   // once, off hot path
    const float skipf = (lane == 0 || myLab != prevLab) ? 1.0f : 0.0f;

    // prologue: stage tiles 0, 1, 2 (48 loads in flight)
    stage_tile(src,               sbuf,               lane);
    stage_tile(src +     TT * VV, sbuf +     TT * VV, lane);
    stage_tile(src + 2 * TT * VV, sbuf + 2 * TT * VV, lane);
    asm volatile("s_waitcnt vmcnt(32)" ::: "memory");   // tile 0 resident

    float cpb[TT], cpl[TT], npb[TT], npl[TT];
    prep_p(sbuf, myLab, cpb, cpl);

    // t = 0 init: only s=0, s=1 reachable (lane 0)
    float a0   = (lane == 0) ? cpb[0] : 0.0f;
    float a1   = (lane == 0) ? cpl[0] : 0.0f;
    float a128 = 0.0f;
    float logC = 0.0f;

    for (int k = 0; k < NT; ++k) {
        if (k + 3 < NT)
            stage_tile(src + (size_t)(k + 3) * TT * VV,
                       sbuf + ((k + 3) % NBUF) * TT * VV, lane);

        if (k + 1 < NT) {
            // outstanding tiles after the issue above: k+1 .. min(k+3, NT-1)
            // wait until tile k+1's 16 loads have landed
            if      (k + 3 < NT) asm volatile("s_waitcnt vmcnt(32)" ::: "memory");
            else if (k + 2 < NT) asm volatile("s_waitcnt vmcnt(16)" ::: "memory");
            else                 asm volatile("s_waitcnt vmcnt(0)"  ::: "memory");
            prep_p(sbuf + ((k + 1) % NBUF) * TT * VV, myLab, npb, npl);
        }

        #pragma unroll
        for (int tt = 0; tt < TT; ++tt) {
            if (!(k == 0 && tt == 0))
                dp_step(a0, a1, a128, cpb[tt], cpl[tt], skipf);
            if ((tt & 7) == 7)
                rescale(a0, a1, a128, logC);   // every 8 steps
        }

        if (k + 1 < NT) {
            #pragma unroll
            for (int tt = 0; tt < TT; ++tt) { cpb[tt] = npb[tt]; cpl[tt] = npl[tt]; }
        }
    }

    // loss = -ln(P) = -ln2 * (logC + log2(alpha[128] + alpha[127])), on lane 63
    if (lane == 63) {
        float tail = fmaxf(a128 + a1, 1e-37f);
        out[b] = -LN2F * (logC + flog2(tail));
    }
}

extern "C" void kernel_launch(void* const* d_in, const int* in_sizes, int n_in,
                              void* d_out, int out_size, void* d_ws, size_t ws_size,
                              hipStream_t stream) {
    const int*   y_true = (const int*)d_in[0];
    const float* y_pred = (const float*)d_in[1];
    float*       out    = (float*)d_out;
    ctc_kernel<<<dim3(BB), dim3(64), 0, stream>>>(y_true, y_pred, out);
}